// Round 13
// baseline (129.968 us; speedup 1.0000x reference)
//
#include <hip/hip_runtime.h>
#include <stdint.h>

typedef unsigned short u16;
typedef __attribute__((ext_vector_type(8))) short bf16x8;
typedef __attribute__((ext_vector_type(4))) float f32x4;

#define NB 8
#define SEQ 1024
#define DDIM 1024
#define NP 128
#define NT 8
#define GK 1024           // K for all GEMMs
#define NKT 16            // GK/64

__device__ __forceinline__ u16 f2b(float f){
  union { float f; uint32_t u; } v; v.f = f;
  return (u16)((v.u + 0x7FFFu + ((v.u >> 16) & 1u)) >> 16);
}
__device__ __forceinline__ float b2f(u16 h){
  union { uint32_t u; float f; } v; v.u = ((uint32_t)h) << 16; return v.f;
}

__device__ __forceinline__ void load_lds16(const void* g, void* l){
  __builtin_amdgcn_global_load_lds((const __attribute__((address_space(1))) void*)g,
                                   (__attribute__((address_space(3))) void*)l,
                                   16, 0, 0);
}

#define MEMFENCE asm volatile("" ::: "memory")
#define SBAR() do { MEMFENCE; __builtin_amdgcn_s_barrier(); MEMFENCE; } while(0)

// ------- merged prep: f32->bf16 convert of x + 2 weight transposes + rowsum/d_out zero -------
__global__ __launch_bounds__(256) void prep_kernel(const float* __restrict__ x,
                                                   u16* __restrict__ xb,
                                                   const float* __restrict__ W0,
                                                   const float* __restrict__ W1,
                                                   u16* __restrict__ T0,
                                                   u16* __restrict__ T1,
                                                   float* __restrict__ rowsum,
                                                   float* __restrict__ dout){
  __shared__ float tile[32][33];
  const int bid = blockIdx.x;
  const int tid = threadIdx.x;
  if(bid < 8192){
    int idx = (bid * 256 + tid) * 4;
    float4 v = *(const float4*)(x + idx);
    ushort4 o;
    o.x = f2b(v.x); o.y = f2b(v.y); o.z = f2b(v.z); o.w = f2b(v.w);
    *(ushort4*)(xb + idx) = o;
  } else {
    const int b2 = bid - 8192;                 // 0..2047
    const int z  = b2 >> 10;                   // 0/1 -> which weight
    const int bx = b2 & 31, by = (b2 >> 5) & 31;
    const int tx = tid & 31, ty = tid >> 5;    // 32 x 8
    const float* W = z ? W1 : W0;
    u16* Wt = z ? T1 : T0;
    const int c0 = bx * 32, r0 = by * 32;
    for(int i = ty; i < 32; i += 8)
      tile[i][tx] = W[(size_t)(r0 + i) * DDIM + c0 + tx];
    __syncthreads();
    for(int i = ty; i < 32; i += 8)
      Wt[(size_t)(c0 + i) * DDIM + r0 + tx] = f2b(tile[tx][i]);
    if(z == 0 && by == 0)
      rowsum[bx * 256 + tid] = 0.f;
    if(b2 == 0 && tid == 0)
      dout[0] = 0.f;
  }
}

// ===== 128x128 min-barrier pipelined bf16 GEMM, 2 blocks/CU: epilogue(A[M,1024].Bt[N,1024]^T) =====
// BM=BN=128 BK=64, 4 waves (2x2 of 64x64), DOUBLE-buffered LDS (64 KB -> 2 blocks/CU;
// cross-block wave overlap hides each block's vmcnt/barrier stalls - the m114 mechanism).
// Per K-tile: vmcnt(8) -> barrier -> 16 ds_read + 32 MFMA -> barrier -> stage t+2 into
// the just-freed slot (slot t&1: all waves' reads of it are consumed by MFMAs before
// bar2, so the restage is race-free).
// XOR-swizzled LDS via pre-swizzled global source; bijective XCD swizzle (grid 512).
// MODE 0: C = [relu](acc + bias) -> bf16
// MODE 1: C = exp(acc) -> bf16, rowsum[bz*SEQ+row] += sum_cols exp (atomic)
template<int MODE, bool RELU>
__global__ __launch_bounds__(256, 2) void gemm_bt(
    const u16* __restrict__ A, const u16* __restrict__ Bt,
    const float* __restrict__ bias, float* __restrict__ rowsum,
    u16* __restrict__ Cv,
    int gm, int N, long long bA, long long bB, long long bC)
{
  __shared__ u16 As[2][128][64];   // 32 KB
  __shared__ u16 Bs[2][128][64];   // 32 KB

  const int tid  = threadIdx.x;
  const int lane = tid & 63;
  const int wid  = tid >> 6;   // 0..3
  const int wr   = wid >> 1;   // 0..1 -> M
  const int wc   = wid & 1;    // 0..1 -> N

  // T1: bijective XCD swizzle (gridDim.x = 512 at all call sites, % 8 == 0)
  int id = blockIdx.x;
  const int chunk = gridDim.x >> 3;
  id = (id & 7) * chunk + (id >> 3);
  const int tn = id & 7;
  const int tm = (id >> 3) % gm;
  const int bz = (id >> 3) / gm;

  const char* gAp = (const char*)(A  + (size_t)bz * bA + (size_t)tm * 128 * GK);
  const char* gBp = (const char*)(Bt + (size_t)bz * bB + (size_t)tn * 128 * GK);
  // staging: thread covers row (q*32 + tid>>3), 16B chunk (tid&7); global col
  // pre-swizzled so the linear LDS dest realizes the XOR layout (rule 21).
  const int colg = ((tid & 7) * 16) ^ (((tid >> 3) & 7) << 4);
  const char* gA0 = gAp + (size_t)(tid >> 3) * 2048 + colg;
  const char* gB0 = gBp + (size_t)(tid >> 3) * 2048 + colg;
  char* lA0 = (char*)&As[0][0][0] + tid * 16;
  char* lB0 = (char*)&Bs[0][0][0] + tid * 16;
  const int SLOT = 128 * 64 * 2;   // 16 KB per slot (A or B)

  auto stage = [&](int slot, int tt){   // 8 loads: 4 A-row-groups + 4 B-row-groups
    const int g = tt * 128;
#pragma unroll
    for(int q = 0; q < 4; q++)
      load_lds16(gA0 + (size_t)q * 32 * 2048 + g, lA0 + slot * SLOT + q * 4096);
#pragma unroll
    for(int q = 0; q < 4; q++)
      load_lds16(gB0 + (size_t)q * 32 * 2048 + g, lB0 + slot * SLOT + q * 4096);
  };

  f32x4 acc[4][4];
#pragma unroll
  for(int i = 0; i < 4; i++)
#pragma unroll
    for(int j = 0; j < 4; j++){ acc[i][j][0]=0.f; acc[i][j][1]=0.f; acc[i][j][2]=0.f; acc[i][j][3]=0.f; }

  const int fr = lane & 15, kq = lane >> 4;
  const int a0 = (kq * 16) ^ ((fr & 7) << 4);   // ks=0 byte offset within 128B row
  const int a1 = a0 ^ 64;                       // ks=1
  const char* aRd = (const char*)&As[0][0][0] + (wr * 64 + fr) * 128;
  const char* bRd = (const char*)&Bs[0][0][0] + (wc * 64 + fr) * 128;

  // ---- prologue: stage tiles 0,1 (16 loads in flight) ----
  stage(0, 0);
  stage(1, 1);

  for(int t = 0; t < NKT; ++t){
    const int slot = t & 1;
    if(t < NKT - 1){ asm volatile("s_waitcnt vmcnt(8)" ::: "memory"); }
    else           { asm volatile("s_waitcnt vmcnt(0)" ::: "memory"); }
    SBAR();   // collective: tile t staged for ALL waves

    const char* ab = aRd + slot * SLOT;
    const char* bb = bRd + slot * SLOT;
    bf16x8 av[4], bv[4], aw[4], bw[4];
#pragma unroll
    for(int mi = 0; mi < 4; mi++) av[mi] = *(const bf16x8*)(ab + mi * 2048 + a0);
#pragma unroll
    for(int ni = 0; ni < 4; ni++) bv[ni] = *(const bf16x8*)(bb + ni * 2048 + a0);
#pragma unroll
    for(int mi = 0; mi < 4; mi++) aw[mi] = *(const bf16x8*)(ab + mi * 2048 + a1);
#pragma unroll
    for(int ni = 0; ni < 4; ni++) bw[ni] = *(const bf16x8*)(bb + ni * 2048 + a1);

    __builtin_amdgcn_s_setprio(1);
#pragma unroll
    for(int mi = 0; mi < 4; mi++)
#pragma unroll
      for(int ni = 0; ni < 4; ni++)
        acc[mi][ni] = __builtin_amdgcn_mfma_f32_16x16x32_bf16(av[mi], bv[ni], acc[mi][ni], 0, 0, 0);
#pragma unroll
    for(int mi = 0; mi < 4; mi++)
#pragma unroll
      for(int ni = 0; ni < 4; ni++)
        acc[mi][ni] = __builtin_amdgcn_mfma_f32_16x16x32_bf16(aw[mi], bw[ni], acc[mi][ni], 0, 0, 0);
    __builtin_amdgcn_s_setprio(0);

    SBAR();   // all waves consumed slot t&1 -> safe to restage it
    if(t + 2 < NKT) stage(slot, t + 2);
  }

  // ---- epilogue: C/D layout col=lane&15, row=(lane>>4)*4+reg ----
  const int m0 = tm * 128 + wr * 64;
  const int n0 = tn * 128 + wc * 64;
  const int rq = lane >> 4;

  if(MODE == 0){
#pragma unroll
    for(int ni = 0; ni < 4; ni++){
      const int gcol = n0 + ni * 16 + fr;
      const float bv = bias[gcol];
#pragma unroll
      for(int mi = 0; mi < 4; mi++){
#pragma unroll
        for(int r = 0; r < 4; r++){
          const int grow = m0 + mi * 16 + rq * 4 + r;
          float v = acc[mi][ni][r] + bv;
          if(RELU) v = fmaxf(v, 0.f);
          Cv[(size_t)bz * bC + (size_t)grow * N + gcol] = f2b(v);
        }
      }
    }
  } else {
    float rs[4][4];
#pragma unroll
    for(int mi = 0; mi < 4; mi++)
#pragma unroll
      for(int r = 0; r < 4; r++) rs[mi][r] = 0.f;
#pragma unroll
    for(int ni = 0; ni < 4; ni++){
      const int gcol = n0 + ni * 16 + fr;
#pragma unroll
      for(int mi = 0; mi < 4; mi++){
#pragma unroll
        for(int r = 0; r < 4; r++){
          const int grow = m0 + mi * 16 + rq * 4 + r;
          float e = __expf(acc[mi][ni][r]);
          rs[mi][r] += e;
          Cv[(size_t)bz * bC + (size_t)grow * N + gcol] = f2b(e);
        }
      }
    }
#pragma unroll
    for(int off = 1; off < 16; off <<= 1)
#pragma unroll
      for(int mi = 0; mi < 4; mi++)
#pragma unroll
        for(int r = 0; r < 4; r++) rs[mi][r] += __shfl_xor(rs[mi][r], off);
    if(fr == 0){
#pragma unroll
      for(int mi = 0; mi < 4; mi++)
#pragma unroll
        for(int r = 0; r < 4; r++){
          const int grow = m0 + mi * 16 + rq * 4 + r;
          atomicAdd(&rowsum[bz * SEQ + grow], rs[mi][r]);
        }
    }
  }
}

// ---------------- VW[row][j] = sum_d out_b[row][d] * W_hid[NP+d][j] ----------------
__global__ __launch_bounds__(256) void vw_kernel(const u16* __restrict__ outb,
                                                 const float* __restrict__ Whid,
                                                 float* __restrict__ VW){
  const int row  = blockIdx.x * 4 + (threadIdx.x >> 6);   // 0..8191
  const int lane = threadIdx.x & 63;
  const u16* o = outb + (size_t)row * 1024;
  float s[8] = {0.f,0.f,0.f,0.f,0.f,0.f,0.f,0.f};
#pragma unroll
  for(int h = 0; h < 16; h++){
    const int d = lane + 64 * h;
    const float od = b2f(o[d]);
    const float4 w0 = *(const float4*)(Whid + (size_t)(NP + d) * 8);
    const float4 w1 = *(const float4*)(Whid + (size_t)(NP + d) * 8 + 4);
    s[0] += od * w0.x; s[1] += od * w0.y; s[2] += od * w0.z; s[3] += od * w0.w;
    s[4] += od * w1.x; s[5] += od * w1.y; s[6] += od * w1.z; s[7] += od * w1.w;
  }
#pragma unroll
  for(int off = 1; off < 64; off <<= 1)
#pragma unroll
    for(int j = 0; j < 8; j++) s[j] += __shfl_xor(s[j], off);
  if(lane == 0){
#pragma unroll
    for(int j = 0; j < 8; j++) VW[(size_t)row * 8 + j] = s[j];
  }
}

// ------- em[row][j] = b_hid[j] + p_cla[row]@W_hidP + (P[row] @ VW[bz]) / rowsum[row] -------
__global__ __launch_bounds__(256) void em2_kernel(const u16* __restrict__ scores,
                                                  const float* __restrict__ pcla,
                                                  const float* __restrict__ VW,
                                                  const float* __restrict__ rowsum,
                                                  const float* __restrict__ Whid,
                                                  const float* __restrict__ bhid,
                                                  float* __restrict__ em){
  const int row  = blockIdx.x * 4 + (threadIdx.x >> 6);   // 0..8191
  const int lane = threadIdx.x & 63;
  const int bz   = row >> 10;
  const u16* pr = scores + (size_t)row * 1024;
  const float* vwb = VW + (size_t)bz * 8192;
  float sa[8] = {0.f,0.f,0.f,0.f,0.f,0.f,0.f,0.f};
  float sp[8] = {0.f,0.f,0.f,0.f,0.f,0.f,0.f,0.f};
#pragma unroll
  for(int h = 0; h < 16; h++){
    const int t = lane + 64 * h;
    const float pv = b2f(pr[t]);
    const float4 v0 = *(const float4*)(vwb + (size_t)t * 8);
    const float4 v1 = *(const float4*)(vwb + (size_t)t * 8 + 4);
    sa[0] += pv * v0.x; sa[1] += pv * v0.y; sa[2] += pv * v0.z; sa[3] += pv * v0.w;
    sa[4] += pv * v1.x; sa[5] += pv * v1.y; sa[6] += pv * v1.z; sa[7] += pv * v1.w;
  }
#pragma unroll
  for(int q = 0; q < 2; q++){
    const int p = lane * 2 + q;
    const float pv = pcla[(size_t)row * NP + p];
    const float4 w0 = *(const float4*)(Whid + (size_t)p * 8);
    const float4 w1 = *(const float4*)(Whid + (size_t)p * 8 + 4);
    sp[0] += pv * w0.x; sp[1] += pv * w0.y; sp[2] += pv * w0.z; sp[3] += pv * w0.w;
    sp[4] += pv * w1.x; sp[5] += pv * w1.y; sp[6] += pv * w1.z; sp[7] += pv * w1.w;
  }
#pragma unroll
  for(int off = 1; off < 64; off <<= 1)
#pragma unroll
    for(int j = 0; j < 8; j++){
      sa[j] += __shfl_xor(sa[j], off);
      sp[j] += __shfl_xor(sp[j], off);
    }
  if(lane == 0){
    const float inv = 1.f / rowsum[row];
#pragma unroll
    for(int j = 0; j < 8; j++)
      em[(size_t)row * 8 + j] = sa[j] * inv + sp[j] + bhid[j];
  }
}

// ---------------- CRF NLL per batch (prob-domain chunked scan + tree) ----------------
__global__ __launch_bounds__(256) void crf_kernel(const float* __restrict__ em,
                                                  const int* __restrict__ tags,
                                                  const float* __restrict__ cstart,
                                                  const float* __restrict__ cend,
                                                  const float* __restrict__ ctrans,
                                                  float* __restrict__ out){
  const int b = blockIdx.x;
  const int tid = threadIdx.x;
  const float* emb = em + (size_t)b * SEQ * 8;
  const int* tg = tags + b * SEQ;

  __shared__ float Mbuf[128][64];
  __shared__ float Mbuf2[64][64];
  __shared__ float ls1[128], ls2[64];
  __shared__ float etr_s[64];
  __shared__ float mxs[64];
  __shared__ float red[256];

  if(tid < 64) etr_s[tid] = expf(ctrans[tid]);

  float loc = 0.f;
  for(int t = tid; t < SEQ; t += 256){
    const int tgt = tg[t];
    loc += emb[t * 8 + tgt];
    if(t < SEQ - 1) loc += ctrans[tgt * 8 + tg[t + 1]];
  }
  if(tid == 0) loc += cstart[tg[0]] + cend[tg[SEQ - 1]];
  red[tid] = loc;
  __syncthreads();
  for(int s = 128; s > 0; s >>= 1){
    if(tid < s) red[tid] += red[tid + s];
    __syncthreads();
  }

  if(tid < 128){
    const int c = tid;
    const int t0 = (c == 0) ? 1 : c * 8;
    const int t1 = c * 8 + 8;
    float etr[64];
#pragma unroll
    for(int i = 0; i < 64; i++) etr[i] = etr_s[i];
    float acc[64];
    float ej[8];
#pragma unroll
    for(int j = 0; j < 8; j++) ej[j] = expf(emb[t0 * 8 + j]);
#pragma unroll
    for(int i = 0; i < 8; i++)
#pragma unroll
      for(int j = 0; j < 8; j++) acc[i * 8 + j] = etr[i * 8 + j] * ej[j];
    for(int t = t0 + 1; t < t1; t++){
#pragma unroll
      for(int j = 0; j < 8; j++) ej[j] = expf(emb[t * 8 + j]);
#pragma unroll
      for(int i = 0; i < 8; i++){
        float tmp[8];
#pragma unroll
        for(int j = 0; j < 8; j++){
          float sv = 0.f;
#pragma unroll
          for(int k = 0; k < 8; k++) sv += acc[i * 8 + k] * etr[k * 8 + j];
          tmp[j] = sv * ej[j];
        }
#pragma unroll
        for(int j = 0; j < 8; j++) acc[i * 8 + j] = tmp[j];
      }
    }
    float mx = acc[0];
#pragma unroll
    for(int i = 1; i < 64; i++) mx = fmaxf(mx, acc[i]);
    const float im = 1.f / mx;
#pragma unroll
    for(int i = 0; i < 64; i++) Mbuf[c][i] = acc[i] * im;
    ls1[c] = logf(mx);
  }
  __syncthreads();

  float* src = &Mbuf[0][0];  float* dst = &Mbuf2[0][0];
  float* lsrc = ls1;         float* ldst = ls2;
  for(int n = 64; n >= 1; n >>= 1){
    for(int idx = tid; idx < n * 64; idx += 256){
      const int p = idx >> 6, e = idx & 63, i = e >> 3, j = e & 7;
      const float* Am = src + (size_t)(2 * p) * 64;
      const float* Bm = src + (size_t)(2 * p + 1) * 64;
      float sv = 0.f;
#pragma unroll
      for(int k = 0; k < 8; k++) sv += Am[i * 8 + k] * Bm[k * 8 + j];
      dst[(size_t)p * 64 + e] = sv;
    }
    __syncthreads();
    if(tid < n){
      const float* Cm = dst + (size_t)tid * 64;
      float mx = Cm[0];
#pragma unroll
      for(int i = 1; i < 64; i++) mx = fmaxf(mx, Cm[i]);
      mxs[tid] = 1.f / mx;
      ldst[tid] = lsrc[2 * tid] + lsrc[2 * tid + 1] + logf(mx);
    }
    __syncthreads();
    for(int idx = tid; idx < n * 64; idx += 256)
      dst[idx] *= mxs[idx >> 6];
    __syncthreads();
    float* tf = src; src = dst; dst = tf;
    float* tl = lsrc; lsrc = ldst; ldst = tl;
  }

  if(tid == 0){
    float a0[8];
#pragma unroll
    for(int i = 0; i < 8; i++) a0[i] = expf(cstart[i] + emb[i]);
    float z = 0.f;
#pragma unroll
    for(int j = 0; j < 8; j++){
      float t = 0.f;
#pragma unroll
      for(int i = 0; i < 8; i++) t += a0[i] * src[i * 8 + j];
      z += t * expf(cend[j]);
    }
    const float logZ = logf(z) + lsrc[0];
    atomicAdd(out, logZ - red[0]);
  }
}

// ---------------- launch ----------------
extern "C" void kernel_launch(void* const* d_in, const int* in_sizes, int n_in,
                              void* d_out, int out_size, void* d_ws, size_t ws_size,
                              hipStream_t stream){
  (void)in_sizes; (void)n_in; (void)out_size; (void)ws_size;
  const float* x      = (const float*)d_in[0];
  const float* p_cla  = (const float*)d_in[1];
  const float* W_emo  = (const float*)d_in[2];
  const float* b_emo  = (const float*)d_in[3];
  const float* W_att  = (const float*)d_in[4];
  const float* b_att  = (const float*)d_in[5];
  const float* W_hid  = (const float*)d_in[6];
  const float* b_hid  = (const float*)d_in[7];
  const float* cstart = (const float*)d_in[8];
  const float* cend   = (const float*)d_in[9];
  const float* ctrans = (const float*)d_in[10];
  const int*   tags   = (const int*)d_in[11];

  char* ws = (char*)d_ws;
  const size_t MB = 1u << 20;
  u16*   xb     = (u16*)(ws + 0 * MB);        // 16MB
  u16*   wemoT  = (u16*)(ws + 16 * MB);       // 2MB
  u16*   wattT  = (u16*)(ws + 18 * MB);       // 2MB
  u16*   out_b  = (u16*)(ws + 20 * MB);       // 16MB
  u16*   oatt   = (u16*)(ws + 36 * MB);       // 16MB
  u16*   scores = (u16*)(ws + 52 * MB);       // 16MB (unnormalized exp, bf16)
  float* VW     = (float*)(ws + 68 * MB);     // 256KB
  float* em     = (float*)(ws + 69 * MB);     // 256KB
  float* rowsum = (float*)(ws + 70 * MB);     // 32KB

  const long long bs = (long long)SEQ * DDIM;

  // convert x + transpose both weights + zero rowsum/d_out, one launch
  prep_kernel<<<8192 + 2048, 256, 0, stream>>>(x, xb, W_emo, W_att, wemoT, wattT,
                                               rowsum, (float*)d_out);

  // out = relu(x @ W_emo + b_emo) ; grid = 64*8 = 512, 2 blocks/CU
  gemm_bt<0, true><<<512, 256, 0, stream>>>(
      xb, wemoT, b_emo, nullptr, out_b, 64, DDIM, 0, 0, 0);
  // out_att = out @ W_att + b_att
  gemm_bt<0, false><<<512, 256, 0, stream>>>(
      out_b, wattT, b_att, nullptr, oatt, 64, DDIM, 0, 0, 0);
  // scores[b] = exp(out_att[b] @ out[b]^T) (bf16) + rowsum atomics ; 8*8*8 = 512
  gemm_bt<1, false><<<512, 256, 0, stream>>>(
      oatt, out_b, nullptr, rowsum, scores, 8, SEQ, bs, bs, bs);
  // VW[row] = out[row] @ W_hid[NP:,:]  (vectorized, no atomics)
  vw_kernel<<<2048, 256, 0, stream>>>(out_b, W_hid, VW);
  // em = b_hid + p_cla@W_hid[:NP,:] + (P @ VW)/rowsum
  em2_kernel<<<2048, 256, 0, stream>>>(scores, p_cla, VW, rowsum, W_hid, b_hid, em);
  // CRF NLL -> atomicAdd into d_out (zeroed by prep)
  crf_kernel<<<NB, 256, 0, stream>>>(em, tags, cstart, cend, ctrans, (float*)d_out);
}

// Round 14
// 125.487 us; speedup vs baseline: 1.0357x; 1.0357x over previous
//
#include <hip/hip_runtime.h>
#include <stdint.h>

typedef unsigned short u16;
typedef __attribute__((ext_vector_type(8))) short bf16x8;
typedef __attribute__((ext_vector_type(4))) float f32x4;

#define NB 8
#define SEQ 1024
#define DDIM 1024
#define NP 128
#define NT 8
#define GK 1024           // K for all GEMMs
#define NKT 16            // GK/64

__device__ __forceinline__ u16 f2b(float f){
  union { float f; uint32_t u; } v; v.f = f;
  return (u16)((v.u + 0x7FFFu + ((v.u >> 16) & 1u)) >> 16);
}
__device__ __forceinline__ float b2f(u16 h){
  union { uint32_t u; float f; } v; v.u = ((uint32_t)h) << 16; return v.f;
}

__device__ __forceinline__ void load_lds16(const void* g, void* l){
  __builtin_amdgcn_global_load_lds((const __attribute__((address_space(1))) void*)g,
                                   (__attribute__((address_space(3))) void*)l,
                                   16, 0, 0);
}

#define MEMFENCE asm volatile("" ::: "memory")
#define SBAR() do { MEMFENCE; __builtin_amdgcn_s_barrier(); MEMFENCE; } while(0)

// ------- merged prep: f32->bf16 convert of x + 2 weight transposes + rowsum/d_out zero -------
__global__ __launch_bounds__(256) void prep_kernel(const float* __restrict__ x,
                                                   u16* __restrict__ xb,
                                                   const float* __restrict__ W0,
                                                   const float* __restrict__ W1,
                                                   u16* __restrict__ T0,
                                                   u16* __restrict__ T1,
                                                   float* __restrict__ rowsum,
                                                   float* __restrict__ dout){
  __shared__ float tile[32][33];
  const int bid = blockIdx.x;
  const int tid = threadIdx.x;
  if(bid < 8192){
    int idx = (bid * 256 + tid) * 4;
    float4 v = *(const float4*)(x + idx);
    ushort4 o;
    o.x = f2b(v.x); o.y = f2b(v.y); o.z = f2b(v.z); o.w = f2b(v.w);
    *(ushort4*)(xb + idx) = o;
  } else {
    const int b2 = bid - 8192;                 // 0..2047
    const int z  = b2 >> 10;                   // 0/1 -> which weight
    const int bx = b2 & 31, by = (b2 >> 5) & 31;
    const int tx = tid & 31, ty = tid >> 5;    // 32 x 8
    const float* W = z ? W1 : W0;
    u16* Wt = z ? T1 : T0;
    const int c0 = bx * 32, r0 = by * 32;
    for(int i = ty; i < 32; i += 8)
      tile[i][tx] = W[(size_t)(r0 + i) * DDIM + c0 + tx];
    __syncthreads();
    for(int i = ty; i < 32; i += 8)
      Wt[(size_t)(c0 + i) * DDIM + r0 + tx] = f2b(tile[tx][i]);
    if(z == 0 && by == 0)
      rowsum[bx * 256 + tid] = 0.f;
    if(b2 == 0 && tid == 0)
      dout[0] = 0.f;
  }
}

// ============ minimal-barrier pipelined bf16 GEMM: C = epilogue(A[M,1024] . Bt[N,1024]^T) ============
// BM=256 BN=128 BK=64, 8 waves (4Mx2N), TRIPLE-buffered LDS.
// ONE barrier + ONE counted vmcnt per K-tile; waves free-run within the tile.
// XOR-swizzled LDS via pre-swizzled global source; bijective XCD swizzle.
// NOTE: s_setprio removed this round (A/B vs R12; m190 says it can hurt lockstep GEMMs).
// MODE 0: C = [relu](acc + bias) -> bf16
// MODE 1: C = exp(acc) -> bf16, rowsum[bz*SEQ+row] += sum_cols exp (atomic)
template<int MODE, bool RELU>
__global__ __launch_bounds__(512, 2) void gemm_bt(
    const u16* __restrict__ A, const u16* __restrict__ Bt,
    const float* __restrict__ bias, float* __restrict__ rowsum,
    u16* __restrict__ Cv,
    int gm, int N, long long bA, long long bB, long long bC)
{
  __shared__ u16 As[3][256][64];   // 96 KB
  __shared__ u16 Bs[3][128][64];   // 48 KB

  const int tid  = threadIdx.x;
  const int lane = tid & 63;
  const int wid  = tid >> 6;   // 0..7
  const int wr   = wid >> 1;   // 0..3 -> M
  const int wc   = wid & 1;    // 0..1 -> N

  // T1: bijective XCD swizzle (gridDim.x % 8 == 0 at all call sites)
  int id = blockIdx.x;
  const int chunk = gridDim.x >> 3;
  id = (id & 7) * chunk + (id >> 3);
  const int tn = id & 7;
  const int tm = (id >> 3) % gm;
  const int bz = (id >> 3) / gm;

  const char* gAp = (const char*)(A  + (size_t)bz * bA + (size_t)tm * 256 * GK);
  const char* gBp = (const char*)(Bt + (size_t)bz * bB + (size_t)tn * 128 * GK);
  const int colg = ((tid & 7) * 16) ^ (((tid >> 3) & 7) << 4);
  const char* gA0 = gAp + (size_t)(tid >> 3) * 2048 + colg;
  const char* gB0 = gBp + (size_t)(tid >> 3) * 2048 + colg;
  char* lA0 = (char*)&As[0][0][0] + tid * 16;
  char* lB0 = (char*)&Bs[0][0][0] + tid * 16;
  const int SLA = 256 * 64 * 2;   // bytes per A slot
  const int SLB = 128 * 64 * 2;

  auto stageA = [&](int slot, int tt){   // 4 loads
    const int g = tt * 128;
#pragma unroll
    for(int q = 0; q < 4; q++)
      load_lds16(gA0 + (size_t)q * 64 * 2048 + g, lA0 + slot * SLA + q * 8192);
  };
  auto stageB = [&](int slot, int tt){   // 2 loads
    const int g = tt * 128;
#pragma unroll
    for(int q = 0; q < 2; q++)
      load_lds16(gB0 + (size_t)q * 64 * 2048 + g, lB0 + slot * SLB + q * 8192);
  };

  f32x4 acc[4][4];
#pragma unroll
  for(int i = 0; i < 4; i++)
#pragma unroll
    for(int j = 0; j < 4; j++){ acc[i][j][0]=0.f; acc[i][j][1]=0.f; acc[i][j][2]=0.f; acc[i][j][3]=0.f; }

  const int fr = lane & 15, kq = lane >> 4;
  const int a0 = (kq * 16) ^ ((fr & 7) << 4);   // ks=0 byte offset within 128B row
  const int a1 = a0 ^ 64;                       // ks=1
  const char* aRd = (const char*)&As[0][0][0] + (wr * 64 + fr) * 128;
  const char* bRd = (const char*)&Bs[0][0][0] + (wc * 64 + fr) * 128;

  // ---- prologue: stage tiles 0,1 (12 loads in flight) ----
  stageA(0, 0); stageB(0, 0);
  stageA(1, 1); stageB(1, 1);

  int slot = 0, slotp = 2;   // slotp = (t+2)%3
  for(int t = 0; t < NKT; ++t){
    if(t < NKT - 1){ asm volatile("s_waitcnt vmcnt(6)" ::: "memory"); }
    else           { asm volatile("s_waitcnt vmcnt(0)" ::: "memory"); }
    SBAR();   // collective: tile t staged for ALL waves; tile t-1 reads all done

    const char* ab = aRd + slot * SLA;
    const char* bb = bRd + slot * SLB;
    bf16x8 av[4], bv[4], aw[4], bw[4];
#pragma unroll
    for(int mi = 0; mi < 4; mi++) av[mi] = *(const bf16x8*)(ab + mi * 2048 + a0);
#pragma unroll
    for(int ni = 0; ni < 4; ni++) bv[ni] = *(const bf16x8*)(bb + ni * 2048 + a0);
#pragma unroll
    for(int mi = 0; mi < 4; mi++) aw[mi] = *(const bf16x8*)(ab + mi * 2048 + a1);
#pragma unroll
    for(int ni = 0; ni < 4; ni++) bw[ni] = *(const bf16x8*)(bb + ni * 2048 + a1);
    if(t + 2 < NKT){ stageA(slotp, t + 2); stageB(slotp, t + 2); }

#pragma unroll
    for(int mi = 0; mi < 4; mi++)
#pragma unroll
      for(int ni = 0; ni < 4; ni++)
        acc[mi][ni] = __builtin_amdgcn_mfma_f32_16x16x32_bf16(av[mi], bv[ni], acc[mi][ni], 0, 0, 0);
#pragma unroll
    for(int mi = 0; mi < 4; mi++)
#pragma unroll
      for(int ni = 0; ni < 4; ni++)
        acc[mi][ni] = __builtin_amdgcn_mfma_f32_16x16x32_bf16(aw[mi], bw[ni], acc[mi][ni], 0, 0, 0);

    slot  = (slot  == 2) ? 0 : slot  + 1;
    slotp = (slotp == 2) ? 0 : slotp + 1;
  }

  // ---- epilogue: C/D layout col=lane&15, row=(lane>>4)*4+reg ----
  const int m0 = tm * 256 + wr * 64;
  const int n0 = tn * 128 + wc * 64;
  const int rq = lane >> 4;

  if(MODE == 0){
#pragma unroll
    for(int ni = 0; ni < 4; ni++){
      const int gcol = n0 + ni * 16 + fr;
      const float bv = bias[gcol];
#pragma unroll
      for(int mi = 0; mi < 4; mi++){
#pragma unroll
        for(int r = 0; r < 4; r++){
          const int grow = m0 + mi * 16 + rq * 4 + r;
          float v = acc[mi][ni][r] + bv;
          if(RELU) v = fmaxf(v, 0.f);
          Cv[(size_t)bz * bC + (size_t)grow * N + gcol] = f2b(v);
        }
      }
    }
  } else {
    float rs[4][4];
#pragma unroll
    for(int mi = 0; mi < 4; mi++)
#pragma unroll
      for(int r = 0; r < 4; r++) rs[mi][r] = 0.f;
#pragma unroll
    for(int ni = 0; ni < 4; ni++){
      const int gcol = n0 + ni * 16 + fr;
#pragma unroll
      for(int mi = 0; mi < 4; mi++){
#pragma unroll
        for(int r = 0; r < 4; r++){
          const int grow = m0 + mi * 16 + rq * 4 + r;
          float e = __expf(acc[mi][ni][r]);
          rs[mi][r] += e;
          Cv[(size_t)bz * bC + (size_t)grow * N + gcol] = f2b(e);
        }
      }
    }
#pragma unroll
    for(int off = 1; off < 16; off <<= 1)
#pragma unroll
      for(int mi = 0; mi < 4; mi++)
#pragma unroll
        for(int r = 0; r < 4; r++) rs[mi][r] += __shfl_xor(rs[mi][r], off);
    if(fr == 0){
#pragma unroll
      for(int mi = 0; mi < 4; mi++)
#pragma unroll
        for(int r = 0; r < 4; r++){
          const int grow = m0 + mi * 16 + rq * 4 + r;
          atomicAdd(&rowsum[bz * SEQ + grow], rs[mi][r]);
        }
    }
  }
}

// ---------------- VW[row][j] = sum_d out_b[row][d] * W_hid[NP+d][j] ----------------
__global__ __launch_bounds__(256) void vw_kernel(const u16* __restrict__ outb,
                                                 const float* __restrict__ Whid,
                                                 float* __restrict__ VW){
  const int row  = blockIdx.x * 4 + (threadIdx.x >> 6);   // 0..8191
  const int lane = threadIdx.x & 63;
  const u16* o = outb + (size_t)row * 1024;
  float s[8] = {0.f,0.f,0.f,0.f,0.f,0.f,0.f,0.f};
#pragma unroll
  for(int h = 0; h < 16; h++){
    const int d = lane + 64 * h;
    const float od = b2f(o[d]);
    const float4 w0 = *(const float4*)(Whid + (size_t)(NP + d) * 8);
    const float4 w1 = *(const float4*)(Whid + (size_t)(NP + d) * 8 + 4);
    s[0] += od * w0.x; s[1] += od * w0.y; s[2] += od * w0.z; s[3] += od * w0.w;
    s[4] += od * w1.x; s[5] += od * w1.y; s[6] += od * w1.z; s[7] += od * w1.w;
  }
#pragma unroll
  for(int off = 1; off < 64; off <<= 1)
#pragma unroll
    for(int j = 0; j < 8; j++) s[j] += __shfl_xor(s[j], off);
  if(lane == 0){
#pragma unroll
    for(int j = 0; j < 8; j++) VW[(size_t)row * 8 + j] = s[j];
  }
}

// ------- em[row][j] = b_hid[j] + p_cla[row]@W_hidP + (P[row] @ VW[bz]) / rowsum[row] -------
__global__ __launch_bounds__(256) void em2_kernel(const u16* __restrict__ scores,
                                                  const float* __restrict__ pcla,
                                                  const float* __restrict__ VW,
                                                  const float* __restrict__ rowsum,
                                                  const float* __restrict__ Whid,
                                                  const float* __restrict__ bhid,
                                                  float* __restrict__ em){
  const int row  = blockIdx.x * 4 + (threadIdx.x >> 6);   // 0..8191
  const int lane = threadIdx.x & 63;
  const int bz   = row >> 10;
  const u16* pr = scores + (size_t)row * 1024;
  const float* vwb = VW + (size_t)bz * 8192;
  float sa[8] = {0.f,0.f,0.f,0.f,0.f,0.f,0.f,0.f};
  float sp[8] = {0.f,0.f,0.f,0.f,0.f,0.f,0.f,0.f};
#pragma unroll
  for(int h = 0; h < 16; h++){
    const int t = lane + 64 * h;
    const float pv = b2f(pr[t]);
    const float4 v0 = *(const float4*)(vwb + (size_t)t * 8);
    const float4 v1 = *(const float4*)(vwb + (size_t)t * 8 + 4);
    sa[0] += pv * v0.x; sa[1] += pv * v0.y; sa[2] += pv * v0.z; sa[3] += pv * v0.w;
    sa[4] += pv * v1.x; sa[5] += pv * v1.y; sa[6] += pv * v1.z; sa[7] += pv * v1.w;
  }
#pragma unroll
  for(int q = 0; q < 2; q++){
    const int p = lane * 2 + q;
    const float pv = pcla[(size_t)row * NP + p];
    const float4 w0 = *(const float4*)(Whid + (size_t)p * 8);
    const float4 w1 = *(const float4*)(Whid + (size_t)p * 8 + 4);
    sp[0] += pv * w0.x; sp[1] += pv * w0.y; sp[2] += pv * w0.z; sp[3] += pv * w0.w;
    sp[4] += pv * w1.x; sp[5] += pv * w1.y; sp[6] += pv * w1.z; sp[7] += pv * w1.w;
  }
#pragma unroll
  for(int off = 1; off < 64; off <<= 1)
#pragma unroll
    for(int j = 0; j < 8; j++){
      sa[j] += __shfl_xor(sa[j], off);
      sp[j] += __shfl_xor(sp[j], off);
    }
  if(lane == 0){
    const float inv = 1.f / rowsum[row];
#pragma unroll
    for(int j = 0; j < 8; j++)
      em[(size_t)row * 8 + j] = sa[j] * inv + sp[j] + bhid[j];
  }
}

// ---------------- CRF NLL per batch (prob-domain chunked scan + tree) ----------------
__global__ __launch_bounds__(256) void crf_kernel(const float* __restrict__ em,
                                                  const int* __restrict__ tags,
                                                  const float* __restrict__ cstart,
                                                  const float* __restrict__ cend,
                                                  const float* __restrict__ ctrans,
                                                  float* __restrict__ out){
  const int b = blockIdx.x;
  const int tid = threadIdx.x;
  const float* emb = em + (size_t)b * SEQ * 8;
  const int* tg = tags + b * SEQ;

  __shared__ float Mbuf[128][64];
  __shared__ float Mbuf2[64][64];
  __shared__ float ls1[128], ls2[64];
  __shared__ float etr_s[64];
  __shared__ float mxs[64];
  __shared__ float red[256];

  if(tid < 64) etr_s[tid] = expf(ctrans[tid]);

  float loc = 0.f;
  for(int t = tid; t < SEQ; t += 256){
    const int tgt = tg[t];
    loc += emb[t * 8 + tgt];
    if(t < SEQ - 1) loc += ctrans[tgt * 8 + tg[t + 1]];
  }
  if(tid == 0) loc += cstart[tg[0]] + cend[tg[SEQ - 1]];
  red[tid] = loc;
  __syncthreads();
  for(int s = 128; s > 0; s >>= 1){
    if(tid < s) red[tid] += red[tid + s];
    __syncthreads();
  }

  if(tid < 128){
    const int c = tid;
    const int t0 = (c == 0) ? 1 : c * 8;
    const int t1 = c * 8 + 8;
    float etr[64];
#pragma unroll
    for(int i = 0; i < 64; i++) etr[i] = etr_s[i];
    float acc[64];
    float ej[8];
#pragma unroll
    for(int j = 0; j < 8; j++) ej[j] = expf(emb[t0 * 8 + j]);
#pragma unroll
    for(int i = 0; i < 8; i++)
#pragma unroll
      for(int j = 0; j < 8; j++) acc[i * 8 + j] = etr[i * 8 + j] * ej[j];
    for(int t = t0 + 1; t < t1; t++){
#pragma unroll
      for(int j = 0; j < 8; j++) ej[j] = expf(emb[t * 8 + j]);
#pragma unroll
      for(int i = 0; i < 8; i++){
        float tmp[8];
#pragma unroll
        for(int j = 0; j < 8; j++){
          float sv = 0.f;
#pragma unroll
          for(int k = 0; k < 8; k++) sv += acc[i * 8 + k] * etr[k * 8 + j];
          tmp[j] = sv * ej[j];
        }
#pragma unroll
        for(int j = 0; j < 8; j++) acc[i * 8 + j] = tmp[j];
      }
    }
    float mx = acc[0];
#pragma unroll
    for(int i = 1; i < 64; i++) mx = fmaxf(mx, acc[i]);
    const float im = 1.f / mx;
#pragma unroll
    for(int i = 0; i < 64; i++) Mbuf[c][i] = acc[i] * im;
    ls1[c] = logf(mx);
  }
  __syncthreads();

  float* src = &Mbuf[0][0];  float* dst = &Mbuf2[0][0];
  float* lsrc = ls1;         float* ldst = ls2;
  for(int n = 64; n >= 1; n >>= 1){
    for(int idx = tid; idx < n * 64; idx += 256){
      const int p = idx >> 6, e = idx & 63, i = e >> 3, j = e & 7;
      const float* Am = src + (size_t)(2 * p) * 64;
      const float* Bm = src + (size_t)(2 * p + 1) * 64;
      float sv = 0.f;
#pragma unroll
      for(int k = 0; k < 8; k++) sv += Am[i * 8 + k] * Bm[k * 8 + j];
      dst[(size_t)p * 64 + e] = sv;
    }
    __syncthreads();
    if(tid < n){
      const float* Cm = dst + (size_t)tid * 64;
      float mx = Cm[0];
#pragma unroll
      for(int i = 1; i < 64; i++) mx = fmaxf(mx, Cm[i]);
      mxs[tid] = 1.f / mx;
      ldst[tid] = lsrc[2 * tid] + lsrc[2 * tid + 1] + logf(mx);
    }
    __syncthreads();
    for(int idx = tid; idx < n * 64; idx += 256)
      dst[idx] *= mxs[idx >> 6];
    __syncthreads();
    float* tf = src; src = dst; dst = tf;
    float* tl = lsrc; lsrc = ldst; ldst = tl;
  }

  if(tid == 0){
    float a0[8];
#pragma unroll
    for(int i = 0; i < 8; i++) a0[i] = expf(cstart[i] + emb[i]);
    float z = 0.f;
#pragma unroll
    for(int j = 0; j < 8; j++){
      float t = 0.f;
#pragma unroll
      for(int i = 0; i < 8; i++) t += a0[i] * src[i * 8 + j];
      z += t * expf(cend[j]);
    }
    const float logZ = logf(z) + lsrc[0];
    atomicAdd(out, logZ - red[0]);
  }
}

// ---------------- launch ----------------
extern "C" void kernel_launch(void* const* d_in, const int* in_sizes, int n_in,
                              void* d_out, int out_size, void* d_ws, size_t ws_size,
                              hipStream_t stream){
  (void)in_sizes; (void)n_in; (void)out_size; (void)ws_size;
  const float* x      = (const float*)d_in[0];
  const float* p_cla  = (const float*)d_in[1];
  const float* W_emo  = (const float*)d_in[2];
  const float* b_emo  = (const float*)d_in[3];
  const float* W_att  = (const float*)d_in[4];
  const float* b_att  = (const float*)d_in[5];
  const float* W_hid  = (const float*)d_in[6];
  const float* b_hid  = (const float*)d_in[7];
  const float* cstart = (const float*)d_in[8];
  const float* cend   = (const float*)d_in[9];
  const float* ctrans = (const float*)d_in[10];
  const int*   tags   = (const int*)d_in[11];

  char* ws = (char*)d_ws;
  const size_t MB = 1u << 20;
  u16*   xb     = (u16*)(ws + 0 * MB);        // 16MB
  u16*   wemoT  = (u16*)(ws + 16 * MB);       // 2MB
  u16*   wattT  = (u16*)(ws + 18 * MB);       // 2MB
  u16*   out_b  = (u16*)(ws + 20 * MB);       // 16MB
  u16*   oatt   = (u16*)(ws + 36 * MB);       // 16MB
  u16*   scores = (u16*)(ws + 52 * MB);       // 16MB (unnormalized exp, bf16)
  float* VW     = (float*)(ws + 68 * MB);     // 256KB
  float* em     = (float*)(ws + 69 * MB);     // 256KB
  float* rowsum = (float*)(ws + 70 * MB);     // 32KB

  const long long bs = (long long)SEQ * DDIM;

  // convert x + transpose both weights + zero rowsum/d_out, one launch
  prep_kernel<<<8192 + 2048, 256, 0, stream>>>(x, xb, W_emo, W_att, wemoT, wattT,
                                               rowsum, (float*)d_out);

  // out = relu(x @ W_emo + b_emo) ; grid = 32*8 = 256
  gemm_bt<0, true><<<256, 512, 0, stream>>>(
      xb, wemoT, b_emo, nullptr, out_b, 32, DDIM, 0, 0, 0);
  // out_att = out @ W_att + b_att
  gemm_bt<0, false><<<256, 512, 0, stream>>>(
      out_b, wattT, b_att, nullptr, oatt, 32, DDIM, 0, 0, 0);
  // scores[b] = exp(out_att[b] @ out[b]^T) (bf16) + rowsum atomics ; 4*8*8 = 256
  gemm_bt<1, false><<<256, 512, 0, stream>>>(
      oatt, out_b, nullptr, rowsum, scores, 4, SEQ, bs, bs, bs);
  // VW[row] = out[row] @ W_hid[NP:,:]  (vectorized, no atomics)
  vw_kernel<<<2048, 256, 0, stream>>>(out_b, W_hid, VW);
  // em = b_hid + p_cla@W_hid[:NP,:] + (P @ VW)/rowsum
  em2_kernel<<<2048, 256, 0, stream>>>(scores, p_cla, VW, rowsum, W_hid, b_hid, em);
  // CRF NLL -> atomicAdd into d_out (zeroed by prep)
  crf_kernel<<<NB, 256, 0, stream>>>(em, tags, cstart, cend, ctrans, (float*)d_out);
}